// Round 2
// baseline (482.566 us; speedup 1.0000x reference)
//
#include <hip/hip_runtime.h>
#include <cstdint>

// GARCH scan: B=64, T=2000, F=257, fp32.
//
// v4: register-ring pipeline with compiler-managed waitcnts.
// v3 failed: global_load_lds width=16 needs 16B-aligned GLOBAL addresses;
// row stride 2056 (8 mod 16) and p-offset 1028 (4 mod 16) made 3/4 of all
// chunk addresses misaligned -> zeros in LDS -> zero outputs.
// v4 uses plain global_load_dwordx4 (dword alignment suffices) into a
// 24-slot statically-indexed register ring (23 KB reads in flight/wave),
// a 4-slot LDS ring for the lane transpose, and double-buffered LDS output
// staging for coalesced 16B stores. All vmcnt/lgkm waits are inserted by
// the compiler's per-register scoreboard (counted, pipeline-preserving),
// so no hand op-counting can break correctness.

#define GB 64
#define GT 2000
#define GF 257
#define GEPS 1e-7f

constexpr int S2f   = 2 * GF;        // 514 floats per input row
constexpr int ROWB  = S2f * 4;       // 2056 B input row
constexpr int OROWB = GF * 4;        // 1028 B output row
constexpr int NCH   = GT / 2;        // 1000 chunks of 2 rows
constexpr int RB    = 24;            // register ring slots (23 chunks ahead)
constexpr int UNROLL = 24;           // inner unroll = RB (static indices)

typedef float v4f  __attribute__((ext_vector_type(4)));
typedef float v4fu __attribute__((ext_vector_type(4), aligned(4)));

// one recurrence step; uses a, am1, be, g, e, pw, s0, s1 from scope
#define STEP(mg, pp, cv)                                                  \
  {                                                                       \
    float msq_ = (mg) * (mg);                                             \
    float u_   = fmaf(am1, msq_, a * s0);                                 \
    float v_   = fmaf(e, s0, fmaf(g, s1, be));                            \
    float ns_  = fmaf(u_, 1.0f - (pp), v_ * (pp));                        \
    float cc_  = (mg) - __builtin_amdgcn_sqrtf(ns_ + GEPS);               \
    cc_ = fmaxf(cc_, 0.0f);                                               \
    s1 = fmaxf(fmaf(-pw, cc_ * cc_, msq_), 0.0f);                         \
    s0 = ns_;                                                             \
    (cv) = cc_;                                                           \
  }

__global__ __launch_bounds__(64) void garch_kernel(
    const float* __restrict__ in,
    const float* __restrict__ Alpha,
    const float* __restrict__ beta,
    const float* __restrict__ gamma,
    const float* __restrict__ eta,
    const float* __restrict__ pi,
    float* __restrict__ out)
{
  __shared__ v4f lring[4][64];                 // input transpose ring, 4 KB
  __shared__ __align__(16) float ob[512];      // output staging (2 halves), 2 KB
  __shared__ float td[2 * GT];                 // tail staging, 16 KB

  const int lane = threadIdx.x;
  const int blk  = blockIdx.x;

  if (blk < 256) {
    // ------------- main path: 64 chains (b, f0..f0+63) -------------
    const int b  = blk >> 2;
    const int f0 = (blk & 3) << 6;
    const int f  = f0 + lane;

    const float a   = Alpha[f];
    const float be  = beta[f];
    const float g   = gamma[f];
    const float e   = eta[f];
    const float pw  = pi[f];
    const float am1 = 1.0f - a;

    const uint8_t* gb = (const uint8_t*)in + (size_t)b * GT * ROWB;
    // chunk = 2 rows; lane loads 16B: sub=lane>>4 selects
    // {mag r0, p r0, mag r1, p r1}, q=lane&15 selects 16B within section.
    const int sub = lane >> 4;
    const int q   = lane & 15;
    const uint8_t* gsrc = gb + (size_t)(sub >> 1) * ROWB
                             + (size_t)(sub & 1) * (GF * 4)
                             + (size_t)f0 * 4 + (size_t)q * 16;

    const float* lc0 = (const float*)&lring[0][0];  // slot stride = 256 floats

    uint8_t* stp = (uint8_t*)out + (size_t)b * GT * OROWB
                 + (size_t)(lane >> 4) * OROWB
                 + (size_t)f0 * 4 + (size_t)q * 16;

    v4fu rb[RB];
    // prologue: chunks 2..24 into rb (static slots c%24); chunks 0,1 -> LDS
    #pragma unroll
    for (int c = 2; c <= 24; ++c)
      rb[c % RB] = *(const v4fu*)(gsrc + (size_t)c * (2 * ROWB));
    {
      v4fu t0 = *(const v4fu*)(gsrc);
      v4fu t1 = *(const v4fu*)(gsrc + (size_t)(2 * ROWB));
      lring[0][lane] = t0;
      lring[1][lane] = t1;
    }

    float s0 = 0.0f, s1 = 0.0f;

    // steps s: A prefetch chunk s+25 -> rb[(u+1)%24];
    //          C consume chunk s from lring[u%4], stage cleans in ob;
    //          B write chunk s+2 from rb[(u+2)%24] -> lring[(u+2)%4].
    // 1008 = 42 * 24 steps; guards idle the last 8.
    for (int sbi = 0; sbi < 1008; sbi += UNROLL) {
      #pragma unroll
      for (int u = 0; u < UNROLL; ++u) {
        const int s = sbi + u;
        // A: prefetch (23 chunks = 23 KB in flight)
        if (s + 25 < NCH)
          rb[(u + 1) % RB] =
              *(const v4fu*)(gsrc + (size_t)(s + 25) * (2 * ROWB));
        __builtin_amdgcn_sched_barrier(0);
        // C: consume chunk s (rows 2s, 2s+1)
        if (s < NCH) {
          const float* lc = lc0 + (size_t)(u & 3) * 256;
          const float mg0 = lc[lane];
          const float p0  = lc[64 + lane];
          const float mg1 = lc[128 + lane];
          const float p1  = lc[192 + lane];
          if (s == 0) {                      // carry init from t=0 inputs
            float t = mg0 * (1.0f - p0);
            s0 = s1 = t * t;
          }
          float c0, c1;
          STEP(mg0, p0, c0);
          STEP(mg1, p1, c1);
          const int h = (u >> 1) & 1;        // ob half for group s>>1
          ob[h * 256 + (u & 1) * 128 + lane]      = c0;
          ob[h * 256 + (u & 1) * 128 + 64 + lane] = c1;
          // flush PREVIOUS group's half (written >=2 steps ago; no stall)
          if ((u & 1) && s >= 3) {
            v4f od = ((const v4f*)ob)[(1 - h) * 64 + lane];
            *(v4fu*)stp = od;
            stp += 4 * OROWB;
          }
        }
        // B: stage chunk s+2 into LDS ring
        if (s + 2 < NCH)
          lring[(u + 2) & 3][lane] = rb[(u + 2) % RB];
      }
    }
    // epilogue: flush last group (chunks 998,999 -> half 1, rows 1996..1999)
    {
      v4f od = ((const v4f*)ob)[64 + lane];
      *(v4fu*)stp = od;
    }
  } else {
    // ------------- tail path: chain (b, f=256) -------------
    const int b = blk - 256;
    const float a   = Alpha[GF - 1];
    const float be  = beta[GF - 1];
    const float g   = gamma[GF - 1];
    const float e   = eta[GF - 1];
    const float pw  = pi[GF - 1];
    const float am1 = 1.0f - a;

    const float* prow = in + (size_t)b * GT * S2f;

    // phase 1: gather (mag,p)[f=256] for all 2000 rows into registers,
    // then LDS (lane L handles rows L, L+64, ...).
    float mreg[32], preg[32];
    #pragma unroll
    for (int k = 0; k < 32; ++k) {
      const int t = lane + (k << 6);
      if (t < GT) {
        mreg[k] = prow[(size_t)t * S2f + (GF - 1)];
        preg[k] = prow[(size_t)t * S2f + (2 * GF - 1)];
      }
    }
    #pragma unroll
    for (int k = 0; k < 32; ++k) {
      const int t = lane + (k << 6);
      if (t < GT) {
        td[2 * t]     = mreg[k];
        td[2 * t + 1] = preg[k];
      }
    }
    __syncthreads();

    // phase 2: serial chain, 16-row batches (reads hoisted into regs),
    // all lanes compute redundantly; lane r keeps row 16j+r.
    float m0 = td[0], p0 = td[1];
    float tt = m0 * (1.0f - p0);
    float s0 = tt * tt, s1 = s0;

    for (int j = 0; j < GT / 16; ++j) {
      float mv[16], pv[16];
      #pragma unroll
      for (int r = 0; r < 16; ++r) {
        mv[r] = td[2 * (16 * j + r)];
        pv[r] = td[2 * (16 * j + r) + 1];
      }
      float creg = 0.0f;
      #pragma unroll
      for (int r = 0; r < 16; ++r) {
        float cc;
        STEP(mv[r], pv[r], cc);
        if (lane == r) creg = cc;
      }
      if (lane < 16)
        out[((size_t)(b * GT + 16 * j + lane)) * GF + (GF - 1)] = creg;
    }
  }
}

extern "C" void kernel_launch(void* const* d_in, const int* in_sizes, int n_in,
                              void* d_out, int out_size, void* d_ws, size_t ws_size,
                              hipStream_t stream) {
  const float* in    = (const float*)d_in[0];
  const float* Alpha = (const float*)d_in[1];
  const float* beta  = (const float*)d_in[2];
  const float* gamma = (const float*)d_in[3];
  const float* eta   = (const float*)d_in[4];
  const float* pi    = (const float*)d_in[5];
  float* out = (float*)d_out;

  // 256 main blocks (b, 64-f group) + 64 tail blocks (f=256)
  garch_kernel<<<320, 64, 0, stream>>>(in, Alpha, beta, gamma, eta, pi, out);
}